// Round 7
// baseline (608.593 us; speedup 1.0000x reference)
//
#include <hip/hip_runtime.h>

// LSTMClassifier round 6: decoupled producer-consumer waves (no __syncthreads
// in the recurrence) + merged-rcp activations (7 trans/cell, was 10).
//   grid = 128 blocks x 1024 threads (16 waves). Block = 16 batch rows.
//   L0 waves (0-7):  h0(k) = f(h0(k-1)),    k = 0..511   -> bufA (6 slots)
//   L1 waves (8-15): h1(m) = f(h0(m), h1(m-1)), m = 0..511 -> bufB (4 slots)
//   Sync: prog[16] per-wave iteration counters in LDS; producers release-store,
//   consumers poll min via ds_read + shfl-min with s_sleep backoff.
//     L0@k waits: minL0 >= k      && minL1 >= k-5   (slot-reuse guard, DA=6)
//     L1@m waits: minL0 >= m+1    && minL1 >= m
//   Wave pairs (u, ph) duplicate MFMA tiles, split the 4 C-rows 2/2.
//   XOR-rotated h layout: conflict-free b64 gathers / <=2-way b16 writes.

typedef _Float16 half8    __attribute__((ext_vector_type(8)));
typedef float    float4_t __attribute__((ext_vector_type(4)));
typedef float    float2_t __attribute__((ext_vector_type(2)));

#define T_STEPS 512
#define SIG_K  (-1.442695040888963f)    // -log2(e)
#define TANH_K (-2.885390081777927f)    // -2*log2(e)
#define DA 6
#define DB 4

__device__ __forceinline__ int hoff(int slot, int row, int kb, int lo) {
    return slot * 1024 + row * 64 + (((kb + row) & 7) << 3) + lo;
}

// wait until min(prog[0..7]) >= thrL0 && min(prog[8..15]) >= thrL1
__device__ __forceinline__ void wait_ge(int* prog, int lane, int thrL0, int thrL1) {
    const int idx = lane & 15;
    const int thr = (idx & 8) ? thrL1 : thrL0;
    for (;;) {
        int v = __hip_atomic_load(&prog[idx], __ATOMIC_RELAXED,
                                  __HIP_MEMORY_SCOPE_WORKGROUP) - thr;
        v = min(v, __shfl_xor(v, 1));
        v = min(v, __shfl_xor(v, 2));
        v = min(v, __shfl_xor(v, 4));
        v = min(v, __shfl_xor(v, 8));
        if (v >= 0) break;
        __builtin_amdgcn_s_sleep(1);
    }
    __threadfence_block();                  // acquire: peers' ds_writes visible
    __builtin_amdgcn_sched_barrier(0);      // no hoisting of data reads above
}

__device__ __forceinline__ void publish(int* prog, int wv, int lane, int val) {
    if (lane == 0)
        __hip_atomic_store(&prog[wv], val, __ATOMIC_RELEASE,
                           __HIP_MEMORY_SCOPE_WORKGROUP);
}

// inputs pre-scaled: zi,zf,zo by -log2e; zg by -2log2e. c updated in place.
// returns h = sigmoid(o)*tanh(c'). 5 exp2 + 2 rcp.
__device__ __forceinline__ float lstm_cell(float zi, float zf, float zg, float zo,
                                           float& c) {
    const float ei = __builtin_amdgcn_exp2f(zi);
    const float ef = __builtin_amdgcn_exp2f(zf);
    const float v  = __builtin_amdgcn_exp2f(zg);
    const float eo = __builtin_amdgcn_exp2f(zo);
    const float pi = 1.f + ei, pf = 1.f + ef, pv = 1.f + v, po = 1.f + eo;
    const float A   = pi * pv;
    const float num = fmaf(c, A, (1.f - v) * pf);
    const float cn  = num * __builtin_amdgcn_rcpf(pf * A);
    c = cn;
    const float u = __builtin_amdgcn_exp2f(cn * TANH_K);
    return (1.f - u) * __builtin_amdgcn_rcpf(po * (1.f + u));
}

extern "C" __global__ __launch_bounds__(1024)
void lstm2_mfma(const float* __restrict__ x,
                const float* __restrict__ w_ih0, const float* __restrict__ w_hh0,
                const float* __restrict__ b_ih0, const float* __restrict__ b_hh0,
                const float* __restrict__ w_ih1, const float* __restrict__ w_hh1,
                const float* __restrict__ b_ih1, const float* __restrict__ b_hh1,
                const float* __restrict__ w_fc,  const float* __restrict__ b_fc,
                float* __restrict__ out)
{
    __shared__ float    x_lds[T_STEPS][16];    // 32 KB
    __shared__ _Float16 bufA[DA * 1024];       // h0 slots, 12 KB
    __shared__ _Float16 bufB[DB * 1024];       // h1 slots, 8 KB
    __shared__ float    hfin[16][68];
    __shared__ int      prog[16];

    const int tid  = threadIdx.x;
    const int wv   = tid >> 6;          // wave 0..15
    const int lane = tid & 63;
    const int cr   = lane & 15;         // A-row (batch) / C-col (unit)
    const int kg   = lane >> 4;         // k-group 0..3
    const int rb   = kg * 4;            // C-frag row base
    const int b0   = blockIdx.x * 16;
    const bool isL0 = (wv < 8);
    const int u    = (wv >> 1) & 3;     // unit tile 0..3
    const int ph   = __builtin_amdgcn_readfirstlane(wv & 1);  // row-pair half
    const int ucol = u * 16 + cr;       // this lane's unit 0..63
    const int wkb  = 2 * u + (cr >> 3); // write-side 8-half block index

    // ---- stage x[b0..b0+15][t] -> x_lds[t][r]; zero bufs; init prog ----
    for (int idx = tid; idx < 16 * T_STEPS; idx += 1024) {
        const int r = idx >> 9, t = idx & (T_STEPS - 1);
        x_lds[t][r] = x[(long)(b0 + r) * T_STEPS + t];
    }
    for (int idx = tid; idx < DA * 1024; idx += 1024) bufA[idx] = (_Float16)0.f;
    for (int idx = tid; idx < DB * 1024; idx += 1024) bufB[idx] = (_Float16)0.f;
    if (tid < 16) prog[tid] = 0;

    // ---- per-lane weight fragments (registers), pre-scaled ----
    half8 wf[4][4];                 // L0 uses [g][0..1]; L1 uses [g][0..3]
    float bias[4], wi0g[4];
    #pragma unroll
    for (int g = 0; g < 4; ++g) {
        const float sc = (g == 2) ? TANH_K : SIG_K;   // gate 2 = g (tanh)
        const int col = g * 64 + ucol;                // PyTorch i,f,g,o
        if (isL0) {
            bias[g] = (b_ih0[col] + b_hh0[col]) * sc;
            wi0g[g] = w_ih0[col] * sc;
            #pragma unroll
            for (int kt = 0; kt < 2; ++kt) {
                const float* src = w_hh0 + col * 64 + kt * 32 + kg * 8;
                #pragma unroll
                for (int i = 0; i < 8; ++i) wf[g][kt][i] = (_Float16)(src[i] * sc);
            }
        } else {
            bias[g] = (b_ih1[col] + b_hh1[col]) * sc;
            #pragma unroll
            for (int kt = 0; kt < 4; ++kt) {
                const int k0 = kt * 32 + kg * 8;   // 0..119 in [h0;h1]
                const float* src = (k0 < 64) ? (w_ih1 + col * 64 + k0)
                                             : (w_hh1 + col * 64 + (k0 - 64));
                #pragma unroll
                for (int i = 0; i < 8; ++i) wf[g][kt][i] = (_Float16)(src[i] * sc);
            }
        }
    }

    const float4_t zero4 = {0.f, 0.f, 0.f, 0.f};
    float cc[2] = {0.f, 0.f};
    float hv[2] = {0.f, 0.f};

    __syncthreads();   // x_lds / zeroed bufs / prog visible

    if (isL0) {
        int rs = DA - 1;                 // slot of h0(k-1); h0(-1)=0 lives in slot 5
        int ws = 0;                      // slot of h0(k)
        for (int k = 0; k < T_STEPS; ++k) {
            wait_ge(prog, lane, k, k - (DA - 1));
            const half8 a0 = *(const half8*)&bufA[hoff(rs, cr, kg,     0)];
            const half8 a1 = *(const half8*)&bufA[hoff(rs, cr, 4 + kg, 0)];
            const float2_t xq = *(const float2_t*)&x_lds[k][rb + 2 * ph];
            float4_t acc[4];
            #pragma unroll
            for (int g = 0; g < 4; ++g) {
                acc[g] = __builtin_amdgcn_mfma_f32_16x16x32_f16(a0, wf[g][0], zero4, 0, 0, 0);
                acc[g] = __builtin_amdgcn_mfma_f32_16x16x32_f16(a1, wf[g][1], acc[g], 0, 0, 0);
            }
            float z[4][2];
            if (ph == 0) {
                #pragma unroll
                for (int g = 0; g < 4; ++g) { z[g][0] = acc[g][0]; z[g][1] = acc[g][1]; }
            } else {
                #pragma unroll
                for (int g = 0; g < 4; ++g) { z[g][0] = acc[g][2]; z[g][1] = acc[g][3]; }
            }
            #pragma unroll
            for (int ii = 0; ii < 2; ++ii) {
                const float xv = xq[ii];
                const float zi = fmaf(xv, wi0g[0], z[0][ii] + bias[0]);
                const float zf = fmaf(xv, wi0g[1], z[1][ii] + bias[1]);
                const float zg = fmaf(xv, wi0g[2], z[2][ii] + bias[2]);
                const float zo = fmaf(xv, wi0g[3], z[3][ii] + bias[3]);
                hv[ii] = lstm_cell(zi, zf, zg, zo, cc[ii]);
                bufA[hoff(ws, rb + 2 * ph + ii, wkb, cr & 7)] = (_Float16)hv[ii];
            }
            publish(prog, wv, lane, k + 1);
            rs = ws; ws = (ws + 1 == DA) ? 0 : ws + 1;
        }
    } else {
        int s0 = 0;                      // slot of h0(m)
        int rB = DB - 1;                 // slot of h1(m-1); h1(-1)=0 in slot 3
        int wB = 0;                      // slot of h1(m)
        for (int m = 0; m < T_STEPS; ++m) {
            wait_ge(prog, lane, m + 1, m);
            const half8 a0  = *(const half8*)&bufA[hoff(s0, cr, kg,     0)];
            const half8 a1  = *(const half8*)&bufA[hoff(s0, cr, 4 + kg, 0)];
            const half8 bh0 = *(const half8*)&bufB[hoff(rB, cr, kg,     0)];
            const half8 bh1 = *(const half8*)&bufB[hoff(rB, cr, 4 + kg, 0)];
            float4_t acc[4];
            #pragma unroll
            for (int g = 0; g < 4; ++g) {
                acc[g] = __builtin_amdgcn_mfma_f32_16x16x32_f16(a0,  wf[g][0], zero4, 0, 0, 0);
                acc[g] = __builtin_amdgcn_mfma_f32_16x16x32_f16(a1,  wf[g][1], acc[g], 0, 0, 0);
                acc[g] = __builtin_amdgcn_mfma_f32_16x16x32_f16(bh0, wf[g][2], acc[g], 0, 0, 0);
                acc[g] = __builtin_amdgcn_mfma_f32_16x16x32_f16(bh1, wf[g][3], acc[g], 0, 0, 0);
            }
            float z[4][2];
            if (ph == 0) {
                #pragma unroll
                for (int g = 0; g < 4; ++g) { z[g][0] = acc[g][0]; z[g][1] = acc[g][1]; }
            } else {
                #pragma unroll
                for (int g = 0; g < 4; ++g) { z[g][0] = acc[g][2]; z[g][1] = acc[g][3]; }
            }
            #pragma unroll
            for (int ii = 0; ii < 2; ++ii) {
                const float zi = z[0][ii] + bias[0];
                const float zf = z[1][ii] + bias[1];
                const float zg = z[2][ii] + bias[2];
                const float zo = z[3][ii] + bias[3];
                hv[ii] = lstm_cell(zi, zf, zg, zo, cc[ii]);
                bufB[hoff(wB, rb + 2 * ph + ii, wkb, cr & 7)] = (_Float16)hv[ii];
            }
            publish(prog, wv, lane, m + 1);
            s0 = (s0 + 1 == DA) ? 0 : s0 + 1;
            rB = wB; wB = (wB + 1 == DB) ? 0 : wB + 1;
        }
    }

    // ---- FC head: h_last = h1(511), held by L1 waves ----
    if (!isL0) {
        hfin[rb + 2 * ph + 0][ucol] = hv[0];
        hfin[rb + 2 * ph + 1][ucol] = hv[1];
    }
    __syncthreads();

    if (tid < 48) {
        const int row = tid / 3, cls = tid - row * 3;
        float s = b_fc[cls];
        const float* wr = w_fc + cls * 64;
        #pragma unroll 8
        for (int uu = 0; uu < 64; ++uu) s += hfin[row][uu] * wr[uu];
        out[(long)(b0 + row) * 3 + cls] = s;
    }
}

extern "C" void kernel_launch(void* const* d_in, const int* in_sizes, int n_in,
                              void* d_out, int out_size, void* d_ws, size_t ws_size,
                              hipStream_t stream) {
    const float* xx     = (const float*)d_in[0];
    const float* w_ih0  = (const float*)d_in[1];
    const float* w_hh0  = (const float*)d_in[2];
    const float* b_ih0  = (const float*)d_in[3];
    const float* b_hh0  = (const float*)d_in[4];
    const float* w_ih1  = (const float*)d_in[5];
    const float* w_hh1  = (const float*)d_in[6];
    const float* b_ih1  = (const float*)d_in[7];
    const float* b_hh1  = (const float*)d_in[8];
    const float* w_fc   = (const float*)d_in[9];
    const float* b_fc   = (const float*)d_in[10];
    float* out = (float*)d_out;

    lstm2_mfma<<<dim3(128), dim3(1024), 0, stream>>>(
        xx, w_ih0, w_hh0, b_ih0, b_hh0,
        w_ih1, w_hh1, b_ih1, b_hh1, w_fc, b_fc, out);
}

// Round 8
// 435.562 us; speedup vs baseline: 1.3973x; 1.3973x over previous
//
#include <hip/hip_runtime.h>

// LSTMClassifier round 7: minimal coupled set, zero duplication.
//   grid = 128 blocks x 256 threads (4 waves). Block = 16 batch rows.
//   Wave w owns units 16w..16w+15 of BOTH layers. In-wave skew-1:
//     iter k:  L0: h0(k)   = f(h0(k-1))            [k <= 511]
//              L1: h1(k-1) = f(h0(k-1), h1(k-2))   [k >= 1]
//   -> both layers consume h0(k-1): ONE pair of A-frag reads feeds 24 MFMAs.
//   ONE s_barrier per iter over 4 equal-work waves. No MFMA duplication.
//   Weights both layers in VGPRs (~96). h0/h1 double-buffered in LDS with
//   XOR-rotated 8-half blocks (conflict-free b64 gathers, <=2-way writes).
//   Merged-rcp activations (5 exp2 + 2 rcp per cell), -log2e pre-scaled.

typedef _Float16 half8    __attribute__((ext_vector_type(8)));
typedef float    float4_t __attribute__((ext_vector_type(4)));

#define T_STEPS 512
#define SIG_K  (-1.442695040888963f)    // -log2(e)
#define TANH_K (-2.885390081777927f)    // -2*log2(e)

__device__ __forceinline__ int hoff(int slot, int row, int kb, int lo) {
    return slot * 1024 + row * 64 + (((kb + row) & 7) << 3) + lo;
}

// inputs pre-scaled: zi,zf,zo by -log2e; zg by -2log2e. c updated in place.
// returns h = sigmoid(o)*tanh(c'). 5 exp2 + 2 rcp.
__device__ __forceinline__ float lstm_cell(float zi, float zf, float zg, float zo,
                                           float& c) {
    const float ei = __builtin_amdgcn_exp2f(zi);
    const float ef = __builtin_amdgcn_exp2f(zf);
    const float v  = __builtin_amdgcn_exp2f(zg);
    const float eo = __builtin_amdgcn_exp2f(zo);
    const float pi = 1.f + ei, pf = 1.f + ef, pv = 1.f + v, po = 1.f + eo;
    const float A   = pi * pv;
    const float num = fmaf(c, A, (1.f - v) * pf);
    const float cn  = num * __builtin_amdgcn_rcpf(pf * A);
    c = cn;
    const float u = __builtin_amdgcn_exp2f(cn * TANH_K);
    return (1.f - u) * __builtin_amdgcn_rcpf(po * (1.f + u));
}

extern "C" __global__ __launch_bounds__(256, 1)
void lstm2_mfma(const float* __restrict__ x,
                const float* __restrict__ w_ih0, const float* __restrict__ w_hh0,
                const float* __restrict__ b_ih0, const float* __restrict__ b_hh0,
                const float* __restrict__ w_ih1, const float* __restrict__ w_hh1,
                const float* __restrict__ b_ih1, const float* __restrict__ b_hh1,
                const float* __restrict__ w_fc,  const float* __restrict__ b_fc,
                float* __restrict__ out)
{
    __shared__ float    x_lds[T_STEPS][16];    // 32 KB
    __shared__ _Float16 bufA[2 * 1024];        // h0, 2 slots, 4 KB
    __shared__ _Float16 bufB[2 * 1024];        // h1, 2 slots, 4 KB
    __shared__ float    hfin[16][68];

    const int tid  = threadIdx.x;
    const int wv   = tid >> 6;          // wave 0..3 = unit tile
    const int lane = tid & 63;
    const int cr   = lane & 15;         // A-row (batch) / C-col (unit)
    const int kg   = lane >> 4;         // k-group 0..3
    const int rb   = kg * 4;            // C-frag row base
    const int b0   = blockIdx.x * 16;
    const int ucol = wv * 16 + cr;      // this lane's unit 0..63
    const int wkb  = 2 * wv + (cr >> 3);// write-side 8-half block index

    // ---- stage x[b0..b0+15][t] -> x_lds[t][r]; zero h bufs ----
    for (int idx = tid; idx < 16 * T_STEPS; idx += 256) {
        const int r = idx >> 9, t = idx & (T_STEPS - 1);
        x_lds[t][r] = x[(long)(b0 + r) * T_STEPS + t];
    }
    for (int idx = tid; idx < 2 * 1024; idx += 256) {
        bufA[idx] = (_Float16)0.f;
        bufB[idx] = (_Float16)0.f;
    }

    // ---- per-lane weight fragments, BOTH layers, pre-scaled ----
    half8 w0f[4][2], w1f[4][4];
    float bias0[4], bias1[4], wi0[4];
    #pragma unroll
    for (int g = 0; g < 4; ++g) {
        const float sc = (g == 2) ? TANH_K : SIG_K;   // gate 2 = g (tanh)
        const int col = g * 64 + ucol;                // PyTorch i,f,g,o
        bias0[g] = (b_ih0[col] + b_hh0[col]) * sc;
        wi0[g]   = w_ih0[col] * sc;
        bias1[g] = (b_ih1[col] + b_hh1[col]) * sc;
        #pragma unroll
        for (int kt = 0; kt < 2; ++kt) {
            const float* src = w_hh0 + col * 64 + kt * 32 + kg * 8;
            #pragma unroll
            for (int i = 0; i < 8; ++i) w0f[g][kt][i] = (_Float16)(src[i] * sc);
        }
        #pragma unroll
        for (int kt = 0; kt < 4; ++kt) {
            const int k0 = kt * 32 + kg * 8;   // 0..119 in [h0;h1]
            const float* src = (k0 < 64) ? (w_ih1 + col * 64 + k0)
                                         : (w_hh1 + col * 64 + (k0 - 64));
            #pragma unroll
            for (int i = 0; i < 8; ++i) w1f[g][kt][i] = (_Float16)(src[i] * sc);
        }
    }

    const float4_t zero4 = {0.f, 0.f, 0.f, 0.f};
    float c0[4] = {0.f,0.f,0.f,0.f}, c1[4] = {0.f,0.f,0.f,0.f};
    float h1v[4] = {0.f,0.f,0.f,0.f};

    __syncthreads();   // x_lds + zeroed bufs visible

    for (int k = 0; k <= T_STEPS; ++k) {
        const int sA = (k + 1) & 1;     // slot of h0(k-1)   (h0(-1)=0 in slot 1)
        const int sB = k & 1;           // slot of h1(k-2)   (h1(-1)=0 in slot 1)

        // one set of reads feeds both layers
        const half8 a0  = *(const half8*)&bufA[hoff(sA, cr, kg,     0)];
        const half8 a1  = *(const half8*)&bufA[hoff(sA, cr, 4 + kg, 0)];
        const half8 bh0 = *(const half8*)&bufB[hoff(sB, cr, kg,     0)];
        const half8 bh1 = *(const half8*)&bufB[hoff(sB, cr, 4 + kg, 0)];

        if (k < T_STEPS) {              // ---- L0: h0(k) ----
            float4_t acc[4];
            #pragma unroll
            for (int g = 0; g < 4; ++g) {
                acc[g] = __builtin_amdgcn_mfma_f32_16x16x32_f16(a0, w0f[g][0], zero4, 0, 0, 0);
                acc[g] = __builtin_amdgcn_mfma_f32_16x16x32_f16(a1, w0f[g][1], acc[g], 0, 0, 0);
            }
            const float4_t xq = *(const float4_t*)&x_lds[k][rb];
            #pragma unroll
            for (int i = 0; i < 4; ++i) {
                const float xv = xq[i];
                const float zi = fmaf(xv, wi0[0], acc[0][i] + bias0[0]);
                const float zf = fmaf(xv, wi0[1], acc[1][i] + bias0[1]);
                const float zg = fmaf(xv, wi0[2], acc[2][i] + bias0[2]);
                const float zo = fmaf(xv, wi0[3], acc[3][i] + bias0[3]);
                const float h = lstm_cell(zi, zf, zg, zo, c0[i]);
                bufA[hoff(k & 1, rb + i, wkb, cr & 7)] = (_Float16)h;
            }
        }

        if (k >= 1) {                   // ---- L1: h1(k-1) ----
            float4_t acc[4];
            #pragma unroll
            for (int g = 0; g < 4; ++g) {
                acc[g] = __builtin_amdgcn_mfma_f32_16x16x32_f16(a0,  w1f[g][0], zero4, 0, 0, 0);
                acc[g] = __builtin_amdgcn_mfma_f32_16x16x32_f16(a1,  w1f[g][1], acc[g], 0, 0, 0);
                acc[g] = __builtin_amdgcn_mfma_f32_16x16x32_f16(bh0, w1f[g][2], acc[g], 0, 0, 0);
                acc[g] = __builtin_amdgcn_mfma_f32_16x16x32_f16(bh1, w1f[g][3], acc[g], 0, 0, 0);
            }
            #pragma unroll
            for (int i = 0; i < 4; ++i) {
                const float zi = acc[0][i] + bias1[0];
                const float zf = acc[1][i] + bias1[1];
                const float zg = acc[2][i] + bias1[2];
                const float zo = acc[3][i] + bias1[3];
                h1v[i] = lstm_cell(zi, zf, zg, zo, c1[i]);
                bufB[hoff((k + 1) & 1, rb + i, wkb, cr & 7)] = (_Float16)h1v[i];
            }
        }

        __syncthreads();    // writes of iter k visible at iter k+1
    }

    // ---- FC head: h_last = h1(511) in h1v ----
    #pragma unroll
    for (int i = 0; i < 4; ++i)
        hfin[rb + i][ucol] = h1v[i];
    __syncthreads();

    if (tid < 48) {
        const int row = tid / 3, cls = tid - row * 3;
        float s = b_fc[cls];
        const float* wr = w_fc + cls * 64;
        #pragma unroll 8
        for (int uu = 0; uu < 64; ++uu) s += hfin[row][uu] * wr[uu];
        out[(long)(b0 + row) * 3 + cls] = s;
    }
}

extern "C" void kernel_launch(void* const* d_in, const int* in_sizes, int n_in,
                              void* d_out, int out_size, void* d_ws, size_t ws_size,
                              hipStream_t stream) {
    const float* xx     = (const float*)d_in[0];
    const float* w_ih0  = (const float*)d_in[1];
    const float* w_hh0  = (const float*)d_in[2];
    const float* b_ih0  = (const float*)d_in[3];
    const float* b_hh0  = (const float*)d_in[4];
    const float* w_ih1  = (const float*)d_in[5];
    const float* w_hh1  = (const float*)d_in[6];
    const float* b_ih1  = (const float*)d_in[7];
    const float* b_hh1  = (const float*)d_in[8];
    const float* w_fc   = (const float*)d_in[9];
    const float* b_fc   = (const float*)d_in[10];
    float* out = (float*)d_out;

    lstm2_mfma<<<dim3(128), dim3(256), 0, stream>>>(
        xx, w_ih0, w_hh0, b_ih0, b_hh0,
        w_ih1, w_hh1, b_ih1, b_hh1, w_fc, b_fc, out);
}

// Round 9
// 385.103 us; speedup vs baseline: 1.5803x; 1.1310x over previous
//
#include <hip/hip_runtime.h>

// LSTMClassifier round 8: L0/L1 wave split, 2 waves/SIMD, no duplication.
//   grid = 128 blocks x 512 threads (8 waves). Block = 16 batch rows.
//   Waves 0-3: layer 0, unit tile u = wv   : h0(k)   = f(h0(k-1))  [k <= 511]
//   Waves 4-7: layer 1, unit tile u = wv-4 : h1(k-1) = f(h0(k-1), h1(k-2)) [k >= 1]
//   Both roles read only state published at iter-(k-1)'s barrier -> ONE
//   s_barrier per iter; balanced epilogues (4 cells each) so waves interleave.
//   Weights in VGPRs; XOR-rotated h layout (conflict-free b64 gathers,
//   <=2-way b16 writes); merged-rcp activations (5 exp2 + 2 rcp per cell),
//   -log2e pre-scaled into weights/biases.

typedef _Float16 half8    __attribute__((ext_vector_type(8)));
typedef float    float4_t __attribute__((ext_vector_type(4)));

#define T_STEPS 512
#define SIG_K  (-1.442695040888963f)    // -log2(e)
#define TANH_K (-2.885390081777927f)    // -2*log2(e)

__device__ __forceinline__ int hoff(int slot, int row, int kb, int lo) {
    return slot * 1024 + row * 64 + (((kb + row) & 7) << 3) + lo;
}

// inputs pre-scaled: zi,zf,zo by -log2e; zg by -2log2e. c updated in place.
// returns h = sigmoid(o)*tanh(c'). 5 exp2 + 2 rcp.
__device__ __forceinline__ float lstm_cell(float zi, float zf, float zg, float zo,
                                           float& c) {
    const float ei = __builtin_amdgcn_exp2f(zi);
    const float ef = __builtin_amdgcn_exp2f(zf);
    const float v  = __builtin_amdgcn_exp2f(zg);
    const float eo = __builtin_amdgcn_exp2f(zo);
    const float pi = 1.f + ei, pf = 1.f + ef, pv = 1.f + v, po = 1.f + eo;
    const float A   = pi * pv;
    const float num = fmaf(c, A, (1.f - v) * pf);
    const float cn  = num * __builtin_amdgcn_rcpf(pf * A);
    c = cn;
    const float u = __builtin_amdgcn_exp2f(cn * TANH_K);
    return (1.f - u) * __builtin_amdgcn_rcpf(po * (1.f + u));
}

extern "C" __global__ __launch_bounds__(512, 1)
void lstm2_mfma(const float* __restrict__ x,
                const float* __restrict__ w_ih0, const float* __restrict__ w_hh0,
                const float* __restrict__ b_ih0, const float* __restrict__ b_hh0,
                const float* __restrict__ w_ih1, const float* __restrict__ w_hh1,
                const float* __restrict__ b_ih1, const float* __restrict__ b_hh1,
                const float* __restrict__ w_fc,  const float* __restrict__ b_fc,
                float* __restrict__ out)
{
    __shared__ float    x_lds[T_STEPS][16];    // 32 KB
    __shared__ _Float16 bufA[2 * 1024];        // h0, 2 slots, 4 KB
    __shared__ _Float16 bufB[2 * 1024];        // h1, 2 slots, 4 KB
    __shared__ float    hfin[16][68];

    const int tid  = threadIdx.x;
    const int wv   = tid >> 6;          // wave 0..7
    const int lane = tid & 63;
    const int cr   = lane & 15;         // A-row (batch) / C-col (unit)
    const int kg   = lane >> 4;         // k-group 0..3
    const int rb   = kg * 4;            // C-frag row base
    const int b0   = blockIdx.x * 16;
    const bool isL0 = (wv < 4);
    const int u    = wv & 3;            // unit tile 0..3
    const int ucol = u * 16 + cr;       // this lane's unit 0..63
    const int wkb  = 2 * u + (cr >> 3); // write-side 8-half block index

    // ---- stage x[b0..b0+15][t] -> x_lds[t][r]; zero h bufs ----
    for (int idx = tid; idx < 16 * T_STEPS; idx += 512) {
        const int r = idx >> 9, t = idx & (T_STEPS - 1);
        x_lds[t][r] = x[(long)(b0 + r) * T_STEPS + t];
    }
    for (int idx = tid; idx < 2 * 1024; idx += 512) {
        bufA[idx] = (_Float16)0.f;
        bufB[idx] = (_Float16)0.f;
    }

    // ---- per-lane weight fragments (registers), role-specialized ----
    half8 wf[4][4];                 // L0 uses [g][0..1]; L1 uses [g][0..3]
    float bias[4], wi0[4];
    #pragma unroll
    for (int g = 0; g < 4; ++g) {
        const float sc = (g == 2) ? TANH_K : SIG_K;   // gate 2 = g (tanh)
        const int col = g * 64 + ucol;                // PyTorch i,f,g,o
        if (isL0) {
            bias[g] = (b_ih0[col] + b_hh0[col]) * sc;
            wi0[g]  = w_ih0[col] * sc;
            #pragma unroll
            for (int kt = 0; kt < 2; ++kt) {
                const float* src = w_hh0 + col * 64 + kt * 32 + kg * 8;
                #pragma unroll
                for (int i = 0; i < 8; ++i) wf[g][kt][i] = (_Float16)(src[i] * sc);
            }
        } else {
            bias[g] = (b_ih1[col] + b_hh1[col]) * sc;
            #pragma unroll
            for (int kt = 0; kt < 4; ++kt) {
                const int k0 = kt * 32 + kg * 8;   // 0..119 in [h0;h1]
                const float* src = (k0 < 64) ? (w_ih1 + col * 64 + k0)
                                             : (w_hh1 + col * 64 + (k0 - 64));
                #pragma unroll
                for (int i = 0; i < 8; ++i) wf[g][kt][i] = (_Float16)(src[i] * sc);
            }
        }
    }

    const float4_t zero4 = {0.f, 0.f, 0.f, 0.f};
    float cc[4] = {0.f,0.f,0.f,0.f};
    float hv[4] = {0.f,0.f,0.f,0.f};

    __syncthreads();   // x_lds + zeroed bufs visible

    for (int k = 0; k <= T_STEPS; ++k) {
        const int sA = (k + 1) & 1;     // slot of h0(k-1)  (h0(-1)=0 in slot 1)

        if (isL0) {
            if (k < T_STEPS) {          // ---- L0: h0(k) ----
                const half8 a0 = *(const half8*)&bufA[hoff(sA, cr, kg,     0)];
                const half8 a1 = *(const half8*)&bufA[hoff(sA, cr, 4 + kg, 0)];
                float4_t acc[4];
                #pragma unroll
                for (int g = 0; g < 4; ++g) {
                    acc[g] = __builtin_amdgcn_mfma_f32_16x16x32_f16(a0, wf[g][0], zero4, 0, 0, 0);
                    acc[g] = __builtin_amdgcn_mfma_f32_16x16x32_f16(a1, wf[g][1], acc[g], 0, 0, 0);
                }
                const float4_t xq = *(const float4_t*)&x_lds[k][rb];
                #pragma unroll
                for (int i = 0; i < 4; ++i) {
                    const float xv = xq[i];
                    const float zi = fmaf(xv, wi0[0], acc[0][i] + bias[0]);
                    const float zf = fmaf(xv, wi0[1], acc[1][i] + bias[1]);
                    const float zg = fmaf(xv, wi0[2], acc[2][i] + bias[2]);
                    const float zo = fmaf(xv, wi0[3], acc[3][i] + bias[3]);
                    const float h = lstm_cell(zi, zf, zg, zo, cc[i]);
                    bufA[hoff(k & 1, rb + i, wkb, cr & 7)] = (_Float16)h;
                }
            }
        } else {
            if (k >= 1) {               // ---- L1: h1(k-1) ----
                const int sB = k & 1;   // slot of h1(k-2)  (h1(-1)=0 in slot 1)
                const half8 a0  = *(const half8*)&bufA[hoff(sA, cr, kg,     0)];
                const half8 a1  = *(const half8*)&bufA[hoff(sA, cr, 4 + kg, 0)];
                const half8 bh0 = *(const half8*)&bufB[hoff(sB, cr, kg,     0)];
                const half8 bh1 = *(const half8*)&bufB[hoff(sB, cr, 4 + kg, 0)];
                float4_t acc[4];
                #pragma unroll
                for (int g = 0; g < 4; ++g) {
                    acc[g] = __builtin_amdgcn_mfma_f32_16x16x32_f16(a0,  wf[g][0], zero4, 0, 0, 0);
                    acc[g] = __builtin_amdgcn_mfma_f32_16x16x32_f16(a1,  wf[g][1], acc[g], 0, 0, 0);
                    acc[g] = __builtin_amdgcn_mfma_f32_16x16x32_f16(bh0, wf[g][2], acc[g], 0, 0, 0);
                    acc[g] = __builtin_amdgcn_mfma_f32_16x16x32_f16(bh1, wf[g][3], acc[g], 0, 0, 0);
                }
                #pragma unroll
                for (int i = 0; i < 4; ++i) {
                    const float zi = acc[0][i] + bias[0];
                    const float zf = acc[1][i] + bias[1];
                    const float zg = acc[2][i] + bias[2];
                    const float zo = acc[3][i] + bias[3];
                    hv[i] = lstm_cell(zi, zf, zg, zo, cc[i]);
                    bufB[hoff((k + 1) & 1, rb + i, wkb, cr & 7)] = (_Float16)hv[i];
                }
            }
        }

        __syncthreads();    // writes of iter k visible at iter k+1
    }

    // ---- FC head: h_last = h1(511), held by L1 waves ----
    if (!isL0) {
        #pragma unroll
        for (int i = 0; i < 4; ++i)
            hfin[rb + i][ucol] = hv[i];
    }
    __syncthreads();

    if (tid < 48) {
        const int row = tid / 3, cls = tid - row * 3;
        float s = b_fc[cls];
        const float* wr = w_fc + cls * 64;
        #pragma unroll 8
        for (int uu = 0; uu < 64; ++uu) s += hfin[row][uu] * wr[uu];
        out[(long)(b0 + row) * 3 + cls] = s;
    }
}

extern "C" void kernel_launch(void* const* d_in, const int* in_sizes, int n_in,
                              void* d_out, int out_size, void* d_ws, size_t ws_size,
                              hipStream_t stream) {
    const float* xx     = (const float*)d_in[0];
    const float* w_ih0  = (const float*)d_in[1];
    const float* w_hh0  = (const float*)d_in[2];
    const float* b_ih0  = (const float*)d_in[3];
    const float* b_hh0  = (const float*)d_in[4];
    const float* w_ih1  = (const float*)d_in[5];
    const float* w_hh1  = (const float*)d_in[6];
    const float* b_ih1  = (const float*)d_in[7];
    const float* b_hh1  = (const float*)d_in[8];
    const float* w_fc   = (const float*)d_in[9];
    const float* b_fc   = (const float*)d_in[10];
    float* out = (float*)d_out;

    lstm2_mfma<<<dim3(128), dim3(512), 0, stream>>>(
        xx, w_ih0, w_hh0, b_ih0, b_hh0,
        w_ih1, w_hh1, b_ih1, b_hh1, w_fc, b_fc, out);
}